// Round 4
// baseline (1323.099 us; speedup 1.0000x reference)
//
#include <hip/hip_runtime.h>

#define NN 40000
#define NE 320000
#define TT 4
#define SCAN_CHUNK 1024
#define NBLK_SCAN ((NN + SCAN_CHUNK - 1) / SCAN_CHUNK)  // 40

typedef float vf4 __attribute__((ext_vector_type(4)));

__device__ __forceinline__ float bcastf(float v, int k) {
    return __builtin_bit_cast(float, __builtin_amdgcn_readlane(__builtin_bit_cast(int, v), k));
}
__device__ __forceinline__ int bcasti(int v, int k) {
    return __builtin_amdgcn_readlane(v, k);
}

// ---------------- embedding: h = inputs @ W_emb  [N,16]@[16,64] ----------------
__global__ void emb_kernel(const float* __restrict__ x, const float* __restrict__ W,
                           float* __restrict__ h) {
    int i = blockIdx.x * blockDim.x + threadIdx.x;
    if (i >= NN * 64) return;
    int n = i >> 6, j = i & 63;
    float acc = 0.f;
#pragma unroll
    for (int k = 0; k < 16; ++k) acc = fmaf(x[n * 16 + k], W[k * 64 + j], acc);
    h[i] = acc;
}

// ---- Wfold[k][j] = Wp_e[0][k][j] + Wp_e[0][k+8][j]  (folds tile(ef,(1,2))) ----
__global__ void wfold_kernel(const float* __restrict__ We, float* __restrict__ Wf) {
    int i = threadIdx.x;
    if (i < 128) Wf[i] = We[i] + We[i + 128];
}

// ================= CSR build (once per launch) =================
__global__ void hist_kernel(const int* __restrict__ dst, int* __restrict__ deg) {
    int e = blockIdx.x * blockDim.x + threadIdx.x;
    if (e < NE) atomicAdd(&deg[dst[e]], 1);
}

__global__ void scan1_kernel(const int* __restrict__ deg, int* __restrict__ bsum) {
    __shared__ int sdata[256];
    int b = blockIdx.x, t = threadIdx.x;
    int base = b * SCAN_CHUNK;
    int sum = 0;
    for (int i = t; i < SCAN_CHUNK; i += 256) {
        int idx = base + i;
        sum += (idx < NN) ? deg[idx] : 0;
    }
    sdata[t] = sum;
    __syncthreads();
    for (int off = 128; off > 0; off >>= 1) {
        if (t < off) sdata[t] += sdata[t + off];
        __syncthreads();
    }
    if (t == 0) bsum[b] = sdata[0];
}

__global__ void scan2_kernel(const int* __restrict__ bsum, int* __restrict__ boff,
                             int* __restrict__ rowptr) {
    if (threadIdx.x == 0) {
        int acc = 0;
        for (int i = 0; i < NBLK_SCAN; ++i) {
            boff[i] = acc;
            acc += bsum[i];
        }
        rowptr[NN] = NE;
    }
}

__global__ void scan3_kernel(const int* __restrict__ deg, const int* __restrict__ boff,
                             int* __restrict__ rowptr) {
    __shared__ int ss[256];
    int b = blockIdx.x, t = threadIdx.x;
    int base = b * SCAN_CHUNK + t * 4;
    int v[4], s = 0;
#pragma unroll
    for (int q = 0; q < 4; ++q) {
        int idx = base + q;
        v[q] = (idx < NN) ? deg[idx] : 0;
        s += v[q];
    }
    ss[t] = s;
    __syncthreads();
    for (int off = 1; off < 256; off <<= 1) {
        int add = (t >= off) ? ss[t - off] : 0;
        __syncthreads();
        ss[t] += add;
        __syncthreads();
    }
    int excl = boff[b] + ss[t] - s;
#pragma unroll
    for (int q = 0; q < 4; ++q) {
        int idx = base + q;
        if (idx < NN) rowptr[idx] = excl;
        excl += v[q];
    }
}

__global__ void scatter_kernel(const int* __restrict__ src, const int* __restrict__ dst,
                               int* __restrict__ cursor, int* __restrict__ perm,
                               int* __restrict__ srcp) {
    int e = blockIdx.x * blockDim.x + threadIdx.x;
    if (e >= NE) return;
    int d = dst[e];
    int pos = atomicAdd(&cursor[d], 1);
    perm[pos] = e;
    srcp[pos] = src[e];
}

// -------- permute e_feats into CSR order; all 4 timestep planes at once --------
__global__ void efperm_all_kernel(const float* __restrict__ ef, const int* __restrict__ perm,
                                  float* __restrict__ out) {
    int pos = blockIdx.x * blockDim.x + threadIdx.x;
    if (pos >= NE) return;
    int e = perm[pos];
    const float4* e4 = reinterpret_cast<const float4*>(ef) + (size_t)e * 8;
#pragma unroll
    for (int k = 0; k < 8; ++k) {
        float4 v = e4[k];
        out[0 * (size_t)NE * 8 + pos * 8 + k] = v.x;
        out[1 * (size_t)NE * 8 + pos * 8 + k] = v.y;
        out[2 * (size_t)NE * 8 + pos * 8 + k] = v.z;
        out[3 * (size_t)NE * 8 + pos * 8 + k] = v.w;
    }
}

__global__ void efperm_one_kernel(const float* __restrict__ ef, const int* __restrict__ perm,
                                  int t, float* __restrict__ out) {
    int i = blockIdx.x * blockDim.x + threadIdx.x;
    if (i >= NE * 8) return;
    int pos = i >> 3, k = i & 7;
    int e = perm[pos];
    out[i] = ef[((size_t)e * 8 + k) * 4 + t];
}

// ================= node transforms =================
// 64-wide: A = relu?(X1)@Whs (+X2@Whs[64:]) + rain*Wr, B likewise.
// 8 nodes per wave; grid must be 1250 blocks (5000 waves * 8 = 40000).
__global__ __launch_bounds__(256) void node_ab_kernel(
    const float* __restrict__ X1, int relu1,
    const float* __restrict__ X2, int d2,
    const float* __restrict__ Whs, const float* __restrict__ Whd,
    const float* __restrict__ rain, const float* __restrict__ Wr,
    float* __restrict__ A, float* __restrict__ B) {
    extern __shared__ float sW[];
    const int dtot = 64 + d2;
    float* sWs = sW;
    float* sWd = sW + (dtot << 6);
    for (int i = threadIdx.x; i < (dtot << 6); i += 256) {
        sWs[i] = Whs[i];
        sWd[i] = Whd[i];
    }
    __syncthreads();
    const int lane = threadIdx.x & 63;
    const int wid = (blockIdx.x << 2) + (threadIdx.x >> 6);
    const int n0 = wid << 3;  // 8 nodes per wave
    const float wr = Wr[lane];
    float xv[8], aa[8], bb[8];
#pragma unroll
    for (int p = 0; p < 8; ++p) {
        float x = __builtin_nontemporal_load(&X1[(n0 + p) * 64 + lane]);
        xv[p] = relu1 ? fmaxf(x, 0.f) : x;
        aa[p] = rain[(n0 + p) * TT] * wr;
        bb[p] = 0.f;
    }
#pragma unroll 16
    for (int k = 0; k < 64; ++k) {
        float ws = sWs[(k << 6) + lane];
        float wd = sWd[(k << 6) + lane];
#pragma unroll
        for (int p = 0; p < 8; ++p) {
            float xk = bcastf(xv[p], k);
            aa[p] = fmaf(xk, ws, aa[p]);
            bb[p] = fmaf(xk, wd, bb[p]);
        }
    }
    if (d2) {
#pragma unroll
        for (int p = 0; p < 8; ++p) xv[p] = X2[(n0 + p) * 16 + (lane & 15)];
#pragma unroll
        for (int k = 0; k < 16; ++k) {
            float ws = sWs[((64 + k) << 6) + lane];
            float wd = sWd[((64 + k) << 6) + lane];
#pragma unroll
            for (int p = 0; p < 8; ++p) {
                float xk = bcastf(xv[p], k);
                aa[p] = fmaf(xk, ws, aa[p]);
                bb[p] = fmaf(xk, wd, bb[p]);
            }
        }
    }
#pragma unroll
    for (int p = 0; p < 8; ++p) {
        A[(n0 + p) * 64 + lane] = aa[p];
        B[(n0 + p) * 64 + lane] = bb[p];
    }
}

// fused prop node transform (16-wide out). 625 blocks.
__global__ __launch_bounds__(256) void node_p_kernel(
    const float* __restrict__ X, const float* __restrict__ P, int has_p,
    const float* __restrict__ Whs, const float* __restrict__ Whd,
    const float* __restrict__ We,
    const float* __restrict__ rain, const float* __restrict__ Wr,
    float* __restrict__ Ap, float* __restrict__ Bp) {
    __shared__ float sX[64 * 68];
    __shared__ float sP[64 * 20];
    __shared__ float sWs[1024], sWd[1024], sWe[256];
    for (int i = threadIdx.x; i < 1024; i += 256) {
        sWs[i] = Whs[i];
        sWd[i] = Whd[i];
    }
    sWe[threadIdx.x] = has_p ? We[threadIdx.x] : 0.f;
    const int n0 = blockIdx.x << 6;
    for (int i = threadIdx.x; i < 1024; i += 256) {
        int row = i >> 4, col = (i & 15) << 2;
        const float4 v = *reinterpret_cast<const float4*>(&X[(n0 + row) * 64 + col]);
        float* d = &sX[row * 68 + col];
        d[0] = fmaxf(v.x, 0.f);
        d[1] = fmaxf(v.y, 0.f);
        d[2] = fmaxf(v.z, 0.f);
        d[3] = fmaxf(v.w, 0.f);
    }
    if (has_p) {
        int row = threadIdx.x >> 2, col = (threadIdx.x & 3) << 2;
        const float4 v = *reinterpret_cast<const float4*>(&P[(n0 + row) * 16 + col]);
        float* d = &sP[row * 20 + col];
        d[0] = v.x; d[1] = v.y; d[2] = v.z; d[3] = v.w;
    }
    __syncthreads();
    const int j = threadIdx.x & 15;
    const int nl0 = threadIdx.x >> 4;
    const float wr = Wr[j];
    float a[4], b[4];
#pragma unroll
    for (int q = 0; q < 4; ++q) {
        int n = n0 + nl0 + (q << 4);
        a[q] = rain[n * TT] * wr;
        b[q] = 0.f;
    }
#pragma unroll 8
    for (int k = 0; k < 64; ++k) {
        float wa = sWs[(k << 4) + j];
        float wb = sWd[(k << 4) + j];
#pragma unroll
        for (int q = 0; q < 4; ++q) {
            float x = sX[(nl0 + (q << 4)) * 68 + k];
            a[q] = fmaf(x, wa, a[q]);
            b[q] = fmaf(x, wb, b[q]);
        }
    }
    if (has_p) {
#pragma unroll
        for (int k = 0; k < 16; ++k) {
            float wa = sWe[(k << 4) + j];
#pragma unroll
            for (int q = 0; q < 4; ++q) {
                float x = sP[(nl0 + (q << 4)) * 20 + k];
                a[q] = fmaf(x, wa, a[q]);
            }
        }
    }
#pragma unroll
    for (int q = 0; q < 4; ++q) {
        int n = n0 + nl0 + (q << 4);
        Ap[n * 16 + j] = a[q];
        Bp[n * 16 + j] = b[q];
    }
}

// ================= CSR edge passes =================
// 64-wide. 4 dst nodes per wave, two-phase pipelined gathers. Grid = 2500.
__global__ __launch_bounds__(256) void edge64_csr(
    const float* __restrict__ A, const float* __restrict__ B,
    const float* __restrict__ efp, const float* __restrict__ We,
    const int* __restrict__ rowptr, const int* __restrict__ srcp,
    float* __restrict__ agg, const float* __restrict__ Wrain,
    float* __restrict__ out, int t) {
    __shared__ float sWe[512];
    for (int i = threadIdx.x; i < 512; i += 256) sWe[i] = We[i];
    __syncthreads();
    const int lane = threadIdx.x & 63;
    const int wid = (blockIdx.x << 2) + (threadIdx.x >> 6);
    const int n0 = wid << 2;  // 4 nodes per wave
    int rp[5];
#pragma unroll
    for (int q = 0; q < 5; ++q) rp[q] = rowptr[n0 + q];
    const int beg0 = rp[0];
    // stage up to 64 srcp entries (covers the 4 rows w.h.p.)
    int sv = 0;
    if (beg0 + lane < NE) sv = __builtin_nontemporal_load(&srcp[beg0 + lane]);
    float bq[4], acc[4];
#pragma unroll
    for (int q = 0; q < 4; ++q) {
        bq[q] = __builtin_nontemporal_load(&B[(size_t)(n0 + q) * 64 + lane]);
        acc[q] = 0.f;
    }
    int mdeg = 0;
#pragma unroll
    for (int q = 0; q < 4; ++q) mdeg = max(mdeg, rp[q + 1] - rp[q]);
    const vf4* ef4 = reinterpret_cast<const vf4*>(efp);
    for (int k = 0; k < mdeg; ++k) {
        float av[4];
        vf4 f0[4], f1[4];
        // phase 1: issue 4 independent gathers + stream loads
#pragma unroll
        for (int q = 0; q < 4; ++q) {
            int p = rp[q] + k;
            if (p < rp[q + 1]) {
                int idx = p - beg0;
                int s;
                if (idx < 64) s = bcasti(sv, idx);
                else s = srcp[p];
                av[q] = A[(size_t)s * 64 + lane];
                f0[q] = __builtin_nontemporal_load(&ef4[(size_t)p * 2]);
                f1[q] = __builtin_nontemporal_load(&ef4[(size_t)p * 2 + 1]);
            }
        }
        // phase 2: consume
#pragma unroll
        for (int q = 0; q < 4; ++q) {
            int p = rp[q] + k;
            if (p < rp[q + 1]) {
                float m = av[q] + bq[q];
                m = fmaf(f0[q].x, sWe[0 * 64 + lane], m);
                m = fmaf(f0[q].y, sWe[1 * 64 + lane], m);
                m = fmaf(f0[q].z, sWe[2 * 64 + lane], m);
                m = fmaf(f0[q].w, sWe[3 * 64 + lane], m);
                m = fmaf(f1[q].x, sWe[4 * 64 + lane], m);
                m = fmaf(f1[q].y, sWe[5 * 64 + lane], m);
                m = fmaf(f1[q].z, sWe[6 * 64 + lane], m);
                m = fmaf(f1[q].w, sWe[7 * 64 + lane], m);
                acc[q] += fmaxf(m, 0.f);
            }
        }
    }
#pragma unroll
    for (int q = 0; q < 4; ++q)
        agg[(size_t)(n0 + q) * 64 + lane] = acc[q];
    if (out) {
        const float wr = Wrain[lane];
#pragma unroll
        for (int q = 0; q < 4; ++q) {
            float r = fmaxf(acc[q], 0.f) * wr;
#pragma unroll
            for (int off = 32; off > 0; off >>= 1) r += __shfl_down(r, off);
            if (lane == 0) out[(n0 + q) * TT + t] = r;
        }
    }
}

// 16-wide, with edge-feature term (first prop). 4 nodes per wave, 2-deep prefetch.
__global__ __launch_bounds__(256) void edge16_csr_ef(
    const float* __restrict__ Ap, const float* __restrict__ Bp,
    const float* __restrict__ efp, const float* __restrict__ Wf,
    const int* __restrict__ rowptr, const int* __restrict__ srcp,
    float* __restrict__ aggp) {
    __shared__ float sW[128];
    if (threadIdx.x < 128) sW[threadIdx.x] = Wf[threadIdx.x];
    __syncthreads();
    const int lane = threadIdx.x & 63;
    const int g = lane >> 4, j = lane & 15;
    const int wid = (blockIdx.x * 256 + threadIdx.x) >> 6;
    const int n = (wid << 2) + g;
    const int beg = rowptr[n], end = rowptr[n + 1];
    const float b = __builtin_nontemporal_load(&Bp[n * 16 + j]);
    const vf4* ef4 = reinterpret_cast<const vf4*>(efp);
    float acc = 0.f;
    int s_nxt = (beg + 1 < end) ? srcp[beg + 1] : 0;
    float av = (beg < end) ? Ap[srcp[beg] * 16 + j] : 0.f;
    for (int pos = beg; pos < end; ++pos) {
        float avc = av;
        int s_nn = (pos + 2 < end) ? srcp[pos + 2] : 0;
        if (pos + 1 < end) av = Ap[s_nxt * 16 + j];
        s_nxt = s_nn;
        vf4 f0 = __builtin_nontemporal_load(&ef4[(size_t)pos * 2]);
        vf4 f1 = __builtin_nontemporal_load(&ef4[(size_t)pos * 2 + 1]);
        float m = avc + b;
        m = fmaf(f0.x, sW[0 * 16 + j], m);
        m = fmaf(f0.y, sW[1 * 16 + j], m);
        m = fmaf(f0.z, sW[2 * 16 + j], m);
        m = fmaf(f0.w, sW[3 * 16 + j], m);
        m = fmaf(f1.x, sW[4 * 16 + j], m);
        m = fmaf(f1.y, sW[5 * 16 + j], m);
        m = fmaf(f1.z, sW[6 * 16 + j], m);
        m = fmaf(f1.w, sW[7 * 16 + j], m);
        acc += fmaxf(m, 0.f);
    }
    aggp[n * 16 + j] = acc;
}

// 16-wide, p-term folded into Ap. 4 nodes per wave, 2-deep prefetch. Grid = 2500.
__global__ __launch_bounds__(256) void edge16_csr_pe(
    const float* __restrict__ Ap, const float* __restrict__ Bp,
    const int* __restrict__ rowptr, const int* __restrict__ srcp,
    float* __restrict__ aggp) {
    const int lane = threadIdx.x & 63;
    const int g = lane >> 4, j = lane & 15;
    const int wid = (blockIdx.x * 256 + threadIdx.x) >> 6;
    const int n = (wid << 2) + g;
    const int beg = rowptr[n], end = rowptr[n + 1];
    const float b = __builtin_nontemporal_load(&Bp[n * 16 + j]);
    float acc = 0.f;
    int s_nxt = (beg + 1 < end) ? srcp[beg + 1] : 0;
    float av = (beg < end) ? Ap[srcp[beg] * 16 + j] : 0.f;
    for (int pos = beg; pos < end; ++pos) {
        float avc = av;
        int s_nn = (pos + 2 < end) ? srcp[pos + 2] : 0;
        if (pos + 1 < end) av = Ap[s_nxt * 16 + j];
        s_nxt = s_nn;
        acc += fmaxf(avc + b, 0.f);
    }
    aggp[n * 16 + j] = acc;
}

extern "C" void kernel_launch(void* const* d_in, const int* in_sizes, int n_in,
                              void* d_out, int out_size, void* d_ws, size_t ws_size,
                              hipStream_t stream) {
    (void)in_sizes; (void)n_in; (void)out_size;
    const float* inputs = (const float*)d_in[0];
    const float* e_feats = (const float*)d_in[1];
    const float* rain0 = (const float*)d_in[2];
    const int* src = (const int*)d_in[3];
    const int* dst = (const int*)d_in[4];
    const float* W_emb = (const float*)d_in[5];
    const float* Win_hs = (const float*)d_in[6];
    const float* Win_hd = (const float*)d_in[7];
    const float* Win_e = (const float*)d_in[8];
    const float* Win_r = (const float*)d_in[9];
    const float* Wp_hs = (const float*)d_in[10];
    const float* Wp_hd = (const float*)d_in[11];
    const float* Wp_e = (const float*)d_in[12];
    const float* Wp_r = (const float*)d_in[13];
    const float* Wo_hs = (const float*)d_in[14];
    const float* Wo_hd = (const float*)d_in[15];
    const float* Wo_e = (const float*)d_in[16];
    const float* Wo_r = (const float*)d_in[17];
    const float* W_rain = (const float*)d_in[18];
    float* out = (float*)d_out;

    const size_t NF64 = (size_t)NN * 64;
    const size_t NF16 = (size_t)NN * 16;
    const size_t EF = (size_t)NE * 8;

    const size_t int_bytes = (2 * (size_t)NE + 2 * (size_t)NN + 1 + 128) * 4;
    const size_t need_big = (6 * NF64 + 4 * NF16 + 4 * EF + 128) * 4 + int_bytes;
    const bool big = ws_size >= need_big;

    float* ws = (float*)d_ws;
    float *A, *B, *aggA, *aggB, *aggO, *hemb, *p0, *p1, *Ap, *Bp, *efp, *Wfold;
    if (big) {
        A = ws;    ws += NF64;
        B = ws;    ws += NF64;
        aggA = ws; ws += NF64;
        aggB = ws; ws += NF64;
        aggO = ws; ws += NF64;
        hemb = ws; ws += NF64;
        p0 = ws;   ws += NF16;
        p1 = ws;   ws += NF16;
        Ap = ws;   ws += NF16;
        Bp = ws;   ws += NF16;
        efp = ws;  ws += 4 * EF;
        Wfold = ws; ws += 128;
    } else {
        A = ws;    ws += NF64;
        B = ws;    ws += NF64;
        aggA = ws; ws += NF64;
        aggB = ws; ws += NF64;
        aggO = ws; ws += NF64;
        efp = ws;  ws += EF;
        Wfold = ws; ws += 128;
        hemb = aggO;
        Ap = A;
        Bp = A + NF16;
        p0 = aggA;
        p1 = aggA + NF16;
    }
    int* ip = (int*)ws;
    int* srcp = ip;    ip += NE;
    int* perm = ip;    ip += NE;
    int* rowptr = ip;  ip += NN + 1;
    int* deg = ip;     ip += NN;
    int* bsum = ip;    ip += 64;
    int* boff = ip;    ip += 64;
    int* cursor = deg;

    // ---- CSR build (once) ----
    hipMemsetAsync(deg, 0, NN * sizeof(int), stream);
    hist_kernel<<<(NE + 255) / 256, 256, 0, stream>>>(dst, deg);
    scan1_kernel<<<NBLK_SCAN, 256, 0, stream>>>(deg, bsum);
    scan2_kernel<<<1, 64, 0, stream>>>(bsum, boff, rowptr);
    scan3_kernel<<<NBLK_SCAN, 256, 0, stream>>>(deg, boff, rowptr);
    hipMemcpyAsync(cursor, rowptr, NN * sizeof(int), hipMemcpyDeviceToDevice, stream);
    scatter_kernel<<<(NE + 255) / 256, 256, 0, stream>>>(src, dst, cursor, perm, srcp);
    if (big)
        efperm_all_kernel<<<(NE + 255) / 256, 256, 0, stream>>>(e_feats, perm, efp);

    emb_kernel<<<(NN * 64 + 255) / 256, 256, 0, stream>>>(inputs, W_emb, hemb);
    wfold_kernel<<<1, 128, 0, stream>>>(Wp_e, Wfold);

    for (int t = 0; t < TT; ++t) {
        const float* rain = rain0 + t;
        const float* eft = big ? (efp + (size_t)t * EF) : efp;
        if (!big)
            efperm_one_kernel<<<(NE * 8 + 255) / 256, 256, 0, stream>>>(e_feats, perm, t, efp);

        // ---- IN s=0 ----
        node_ab_kernel<<<1250, 256, 64 * 64 * 2 * sizeof(float), stream>>>(
            (t == 0) ? hemb : aggO, (t > 0) ? 1 : 0, nullptr, 0,
            Win_hs, Win_hd, rain, Win_r, A, B);
        edge64_csr<<<2500, 256, 0, stream>>>(A, B, eft, Win_e, rowptr, srcp, aggA,
                                             nullptr, nullptr, 0);

        // ---- IN s=1 ----
        node_ab_kernel<<<1250, 256, 64 * 64 * 2 * sizeof(float), stream>>>(
            aggA, 1, nullptr, 0, Win_hs + 4096, Win_hd + 4096, rain, Win_r + 64, A, B);
        edge64_csr<<<2500, 256, 0, stream>>>(A, B, eft, Win_e + 512, rowptr, srcp, aggB,
                                             nullptr, nullptr, 0);

        // ---- PROP first call (s=0, edge-level ef with folded weights) ----
        node_p_kernel<<<625, 256, 0, stream>>>(aggB, nullptr, 0, Wp_hs, Wp_hd, nullptr,
                                               rain, Wp_r, Ap, Bp);
        edge16_csr_ef<<<2500, 256, 0, stream>>>(Ap, Bp, eft, Wfold, rowptr, srcp, p0);

        float* pc = p0;
        float* pn = p1;
        for (int s = (t == 0) ? 0 : 1; s < 2; ++s) {
            node_p_kernel<<<625, 256, 0, stream>>>(aggB, pc, 1, Wp_hs + s * 1024,
                                                   Wp_hd + s * 1024, Wp_e + s * 256,
                                                   rain, Wp_r + s * 16, Ap, Bp);
            edge16_csr_pe<<<2500, 256, 0, stream>>>(Ap, Bp, rowptr, srcp, pn);
            float* tmp = pc; pc = pn; pn = tmp;
        }

        // ---- OUT layer (fused rain-output epilogue) ----
        node_ab_kernel<<<1250, 256, 80 * 64 * 2 * sizeof(float), stream>>>(
            aggB, 1, pc, 16, Wo_hs, Wo_hd, rain, Wo_r, A, B);
        edge64_csr<<<2500, 256, 0, stream>>>(A, B, eft, Wo_e, rowptr, srcp, aggO,
                                             W_rain, out, t);
    }
}

// Round 5
// 1077.312 us; speedup vs baseline: 1.2281x; 1.2281x over previous
//
#include <hip/hip_runtime.h>

#define NN 40000
#define NE 320000
#define TT 4
#define SCAN_CHUNK 1024
#define NBLK_SCAN ((NN + SCAN_CHUNK - 1) / SCAN_CHUNK)  // 40

typedef float vf4 __attribute__((ext_vector_type(4)));

__device__ __forceinline__ float bcastf(float v, int k) {
    return __builtin_bit_cast(float, __builtin_amdgcn_readlane(__builtin_bit_cast(int, v), k));
}
__device__ __forceinline__ int bcasti(int v, int k) {
    return __builtin_amdgcn_readlane(v, k);
}

// ---------------- embedding: h = inputs @ W_emb  [N,16]@[16,64] ----------------
__global__ void emb_kernel(const float* __restrict__ x, const float* __restrict__ W,
                           float* __restrict__ h) {
    int i = blockIdx.x * blockDim.x + threadIdx.x;
    if (i >= NN * 64) return;
    int n = i >> 6, j = i & 63;
    float acc = 0.f;
#pragma unroll
    for (int k = 0; k < 16; ++k) acc = fmaf(x[n * 16 + k], W[k * 64 + j], acc);
    h[i] = acc;
}

// ---- Wfold[k][j] = Wp_e[0][k][j] + Wp_e[0][k+8][j]  (folds tile(ef,(1,2))) ----
__global__ void wfold_kernel(const float* __restrict__ We, float* __restrict__ Wf) {
    int i = threadIdx.x;
    if (i < 128) Wf[i] = We[i] + We[i + 128];
}

// ================= CSR build (once per launch) =================
__global__ void hist_kernel(const int* __restrict__ dst, int* __restrict__ deg) {
    int e = blockIdx.x * blockDim.x + threadIdx.x;
    if (e < NE) atomicAdd(&deg[dst[e]], 1);
}

__global__ void scan1_kernel(const int* __restrict__ deg, int* __restrict__ bsum) {
    __shared__ int sdata[256];
    int b = blockIdx.x, t = threadIdx.x;
    int base = b * SCAN_CHUNK;
    int sum = 0;
    for (int i = t; i < SCAN_CHUNK; i += 256) {
        int idx = base + i;
        sum += (idx < NN) ? deg[idx] : 0;
    }
    sdata[t] = sum;
    __syncthreads();
    for (int off = 128; off > 0; off >>= 1) {
        if (t < off) sdata[t] += sdata[t + off];
        __syncthreads();
    }
    if (t == 0) bsum[b] = sdata[0];
}

__global__ void scan2_kernel(const int* __restrict__ bsum, int* __restrict__ boff,
                             int* __restrict__ rowptr) {
    if (threadIdx.x == 0) {
        int acc = 0;
        for (int i = 0; i < NBLK_SCAN; ++i) {
            boff[i] = acc;
            acc += bsum[i];
        }
        rowptr[NN] = NE;
    }
}

__global__ void scan3_kernel(const int* __restrict__ deg, const int* __restrict__ boff,
                             int* __restrict__ rowptr) {
    __shared__ int ss[256];
    int b = blockIdx.x, t = threadIdx.x;
    int base = b * SCAN_CHUNK + t * 4;
    int v[4], s = 0;
#pragma unroll
    for (int q = 0; q < 4; ++q) {
        int idx = base + q;
        v[q] = (idx < NN) ? deg[idx] : 0;
        s += v[q];
    }
    ss[t] = s;
    __syncthreads();
    for (int off = 1; off < 256; off <<= 1) {
        int add = (t >= off) ? ss[t - off] : 0;
        __syncthreads();
        ss[t] += add;
        __syncthreads();
    }
    int excl = boff[b] + ss[t] - s;
#pragma unroll
    for (int q = 0; q < 4; ++q) {
        int idx = base + q;
        if (idx < NN) rowptr[idx] = excl;
        excl += v[q];
    }
}

__global__ void scatter_kernel(const int* __restrict__ src, const int* __restrict__ dst,
                               int* __restrict__ cursor, int* __restrict__ perm,
                               int* __restrict__ srcp) {
    int e = blockIdx.x * blockDim.x + threadIdx.x;
    if (e >= NE) return;
    int d = dst[e];
    int pos = atomicAdd(&cursor[d], 1);
    perm[pos] = e;
    srcp[pos] = src[e];
}

// -------- permute e_feats into CSR order; all 4 timestep planes at once --------
__global__ void efperm_all_kernel(const float* __restrict__ ef, const int* __restrict__ perm,
                                  float* __restrict__ out) {
    int pos = blockIdx.x * blockDim.x + threadIdx.x;
    if (pos >= NE) return;
    int e = perm[pos];
    const float4* e4 = reinterpret_cast<const float4*>(ef) + (size_t)e * 8;
#pragma unroll
    for (int k = 0; k < 8; ++k) {
        float4 v = e4[k];
        out[0 * (size_t)NE * 8 + pos * 8 + k] = v.x;
        out[1 * (size_t)NE * 8 + pos * 8 + k] = v.y;
        out[2 * (size_t)NE * 8 + pos * 8 + k] = v.z;
        out[3 * (size_t)NE * 8 + pos * 8 + k] = v.w;
    }
}

__global__ void efperm_one_kernel(const float* __restrict__ ef, const int* __restrict__ perm,
                                  int t, float* __restrict__ out) {
    int i = blockIdx.x * blockDim.x + threadIdx.x;
    if (i >= NE * 8) return;
    int pos = i >> 3, k = i & 7;
    int e = perm[pos];
    out[i] = ef[((size_t)e * 8 + k) * 4 + t];
}

// ================= node transforms =================
// 64-wide: A = relu?(X1)@Whs (+X2@Whs[64:]) + rain*Wr, B likewise.
// 8 nodes per wave; grid must be 1250 blocks.
__global__ __launch_bounds__(256) void node_ab_kernel(
    const float* __restrict__ X1, int relu1,
    const float* __restrict__ X2, int d2,
    const float* __restrict__ Whs, const float* __restrict__ Whd,
    const float* __restrict__ rain, const float* __restrict__ Wr,
    float* __restrict__ A, float* __restrict__ B) {
    extern __shared__ float sW[];
    const int dtot = 64 + d2;
    float* sWs = sW;
    float* sWd = sW + (dtot << 6);
    for (int i = threadIdx.x; i < (dtot << 6); i += 256) {
        sWs[i] = Whs[i];
        sWd[i] = Whd[i];
    }
    __syncthreads();
    const int lane = threadIdx.x & 63;
    const int wid = (blockIdx.x << 2) + (threadIdx.x >> 6);
    const int n0 = wid << 3;  // 8 nodes per wave
    const float wr = Wr[lane];
    float xv[8], aa[8], bb[8];
#pragma unroll
    for (int p = 0; p < 8; ++p) {
        float x = __builtin_nontemporal_load(&X1[(n0 + p) * 64 + lane]);
        xv[p] = relu1 ? fmaxf(x, 0.f) : x;
        aa[p] = rain[(n0 + p) * TT] * wr;
        bb[p] = 0.f;
    }
#pragma unroll 16
    for (int k = 0; k < 64; ++k) {
        float ws = sWs[(k << 6) + lane];
        float wd = sWd[(k << 6) + lane];
#pragma unroll
        for (int p = 0; p < 8; ++p) {
            float xk = bcastf(xv[p], k);
            aa[p] = fmaf(xk, ws, aa[p]);
            bb[p] = fmaf(xk, wd, bb[p]);
        }
    }
    if (d2) {
#pragma unroll
        for (int p = 0; p < 8; ++p) xv[p] = X2[(n0 + p) * 16 + (lane & 15)];
#pragma unroll
        for (int k = 0; k < 16; ++k) {
            float ws = sWs[((64 + k) << 6) + lane];
            float wd = sWd[((64 + k) << 6) + lane];
#pragma unroll
            for (int p = 0; p < 8; ++p) {
                float xk = bcastf(xv[p], k);
                aa[p] = fmaf(xk, ws, aa[p]);
                bb[p] = fmaf(xk, wd, bb[p]);
            }
        }
    }
#pragma unroll
    for (int p = 0; p < 8; ++p) {
        A[(n0 + p) * 64 + lane] = aa[p];
        B[(n0 + p) * 64 + lane] = bb[p];
    }
}

// fused prop node transform (16-wide out). 625 blocks.
__global__ __launch_bounds__(256) void node_p_kernel(
    const float* __restrict__ X, const float* __restrict__ P, int has_p,
    const float* __restrict__ Whs, const float* __restrict__ Whd,
    const float* __restrict__ We,
    const float* __restrict__ rain, const float* __restrict__ Wr,
    float* __restrict__ Ap, float* __restrict__ Bp) {
    __shared__ float sX[64 * 68];
    __shared__ float sP[64 * 20];
    __shared__ float sWs[1024], sWd[1024], sWe[256];
    for (int i = threadIdx.x; i < 1024; i += 256) {
        sWs[i] = Whs[i];
        sWd[i] = Whd[i];
    }
    sWe[threadIdx.x] = has_p ? We[threadIdx.x] : 0.f;
    const int n0 = blockIdx.x << 6;
    for (int i = threadIdx.x; i < 1024; i += 256) {
        int row = i >> 4, col = (i & 15) << 2;
        const float4 v = *reinterpret_cast<const float4*>(&X[(n0 + row) * 64 + col]);
        float* d = &sX[row * 68 + col];
        d[0] = fmaxf(v.x, 0.f);
        d[1] = fmaxf(v.y, 0.f);
        d[2] = fmaxf(v.z, 0.f);
        d[3] = fmaxf(v.w, 0.f);
    }
    if (has_p) {
        int row = threadIdx.x >> 2, col = (threadIdx.x & 3) << 2;
        const float4 v = *reinterpret_cast<const float4*>(&P[(n0 + row) * 16 + col]);
        float* d = &sP[row * 20 + col];
        d[0] = v.x; d[1] = v.y; d[2] = v.z; d[3] = v.w;
    }
    __syncthreads();
    const int j = threadIdx.x & 15;
    const int nl0 = threadIdx.x >> 4;
    const float wr = Wr[j];
    float a[4], b[4];
#pragma unroll
    for (int q = 0; q < 4; ++q) {
        int n = n0 + nl0 + (q << 4);
        a[q] = rain[n * TT] * wr;
        b[q] = 0.f;
    }
#pragma unroll 8
    for (int k = 0; k < 64; ++k) {
        float wa = sWs[(k << 4) + j];
        float wb = sWd[(k << 4) + j];
#pragma unroll
        for (int q = 0; q < 4; ++q) {
            float x = sX[(nl0 + (q << 4)) * 68 + k];
            a[q] = fmaf(x, wa, a[q]);
            b[q] = fmaf(x, wb, b[q]);
        }
    }
    if (has_p) {
#pragma unroll
        for (int k = 0; k < 16; ++k) {
            float wa = sWe[(k << 4) + j];
#pragma unroll
            for (int q = 0; q < 4; ++q) {
                float x = sP[(nl0 + (q << 4)) * 20 + k];
                a[q] = fmaf(x, wa, a[q]);
            }
        }
    }
#pragma unroll
    for (int q = 0; q < 4; ++q) {
        int n = n0 + nl0 + (q << 4);
        Ap[n * 16 + j] = a[q];
        Bp[n * 16 + j] = b[q];
    }
}

// ================= CSR edge passes =================
// 64-wide. Wave per dst node; srcp staged in-register; 4 gathers in flight.
// Grid = 10000 blocks (4 waves each).
__global__ __launch_bounds__(256) void edge64_csr(
    const float* __restrict__ A, const float* __restrict__ B,
    const float* __restrict__ efp, const float* __restrict__ We,
    const int* __restrict__ rowptr, const int* __restrict__ srcp,
    float* __restrict__ agg, const float* __restrict__ Wrain,
    float* __restrict__ out, int t) {
    const int lane = threadIdx.x & 63;
    const int n = (blockIdx.x << 2) + (threadIdx.x >> 6);
    // per-lane weight column: fixed across edges -> registers, no LDS
    const float w0 = We[0 * 64 + lane], w1 = We[1 * 64 + lane];
    const float w2 = We[2 * 64 + lane], w3 = We[3 * 64 + lane];
    const float w4 = We[4 * 64 + lane], w5 = We[5 * 64 + lane];
    const float w6 = We[6 * 64 + lane], w7 = We[7 * 64 + lane];
    const int beg = rowptr[n], end = rowptr[n + 1];
    const int deg = end - beg;
    // stage this row's src indices (deg <= 64 essentially always)
    int sv = 0;
    if (beg + lane < NE) sv = srcp[beg + lane];
    const float b = __builtin_nontemporal_load(&B[(size_t)n * 64 + lane]);
    const vf4* ef4 = reinterpret_cast<const vf4*>(efp);
    float acc = 0.f;
    for (int k0 = 0; k0 < deg; k0 += 4) {
        float av[4];
        vf4 f0[4], f1[4];
#pragma unroll
        for (int i = 0; i < 4; ++i) {
            int kk = k0 + i;
            if (kk > deg - 1) kk = deg - 1;  // clamped duplicate; masked in consume
            int s = (kk < 64) ? bcasti(sv, kk) : srcp[beg + kk];
            av[i] = A[(size_t)s * 64 + lane];
            f0[i] = ef4[(size_t)(beg + kk) * 2];
            f1[i] = ef4[(size_t)(beg + kk) * 2 + 1];
        }
#pragma unroll
        for (int i = 0; i < 4; ++i) {
            if (k0 + i < deg) {
                float m = av[i] + b;
                m = fmaf(f0[i].x, w0, m);
                m = fmaf(f0[i].y, w1, m);
                m = fmaf(f0[i].z, w2, m);
                m = fmaf(f0[i].w, w3, m);
                m = fmaf(f1[i].x, w4, m);
                m = fmaf(f1[i].y, w5, m);
                m = fmaf(f1[i].z, w6, m);
                m = fmaf(f1[i].w, w7, m);
                acc += fmaxf(m, 0.f);
            }
        }
    }
    __builtin_nontemporal_store(acc, &agg[(size_t)n * 64 + lane]);
    if (out) {
        float r = fmaxf(acc, 0.f) * Wrain[lane];
#pragma unroll
        for (int off = 32; off > 0; off >>= 1) r += __shfl_down(r, off);
        if (lane == 0) out[n * TT + t] = r;
    }
}

// 16-wide, with edge-feature term (first prop). 4 nodes per wave, 2-deep prefetch.
__global__ __launch_bounds__(256) void edge16_csr_ef(
    const float* __restrict__ Ap, const float* __restrict__ Bp,
    const float* __restrict__ efp, const float* __restrict__ Wf,
    const int* __restrict__ rowptr, const int* __restrict__ srcp,
    float* __restrict__ aggp) {
    const int lane = threadIdx.x & 63;
    const int g = lane >> 4, j = lane & 15;
    // per-lane weight column in registers
    float w[8];
#pragma unroll
    for (int k = 0; k < 8; ++k) w[k] = Wf[k * 16 + j];
    const int wid = (blockIdx.x * 256 + threadIdx.x) >> 6;
    const int n = (wid << 2) + g;
    const int beg = rowptr[n], end = rowptr[n + 1];
    const float b = __builtin_nontemporal_load(&Bp[n * 16 + j]);
    const vf4* ef4 = reinterpret_cast<const vf4*>(efp);
    float acc = 0.f;
    int s_nxt = (beg + 1 < end) ? srcp[beg + 1] : 0;
    float av = (beg < end) ? Ap[srcp[beg] * 16 + j] : 0.f;
    for (int pos = beg; pos < end; ++pos) {
        float avc = av;
        int s_nn = (pos + 2 < end) ? srcp[pos + 2] : 0;
        if (pos + 1 < end) av = Ap[s_nxt * 16 + j];
        s_nxt = s_nn;
        vf4 f0 = ef4[(size_t)pos * 2];
        vf4 f1 = ef4[(size_t)pos * 2 + 1];
        float m = avc + b;
        m = fmaf(f0.x, w[0], m);
        m = fmaf(f0.y, w[1], m);
        m = fmaf(f0.z, w[2], m);
        m = fmaf(f0.w, w[3], m);
        m = fmaf(f1.x, w[4], m);
        m = fmaf(f1.y, w[5], m);
        m = fmaf(f1.z, w[6], m);
        m = fmaf(f1.w, w[7], m);
        acc += fmaxf(m, 0.f);
    }
    aggp[n * 16 + j] = acc;
}

// 16-wide, p-term folded into Ap. 4 nodes per wave, 2-deep prefetch. Grid = 2500.
__global__ __launch_bounds__(256) void edge16_csr_pe(
    const float* __restrict__ Ap, const float* __restrict__ Bp,
    const int* __restrict__ rowptr, const int* __restrict__ srcp,
    float* __restrict__ aggp) {
    const int lane = threadIdx.x & 63;
    const int g = lane >> 4, j = lane & 15;
    const int wid = (blockIdx.x * 256 + threadIdx.x) >> 6;
    const int n = (wid << 2) + g;
    const int beg = rowptr[n], end = rowptr[n + 1];
    const float b = __builtin_nontemporal_load(&Bp[n * 16 + j]);
    float acc = 0.f;
    int s_nxt = (beg + 1 < end) ? srcp[beg + 1] : 0;
    float av = (beg < end) ? Ap[srcp[beg] * 16 + j] : 0.f;
    for (int pos = beg; pos < end; ++pos) {
        float avc = av;
        int s_nn = (pos + 2 < end) ? srcp[pos + 2] : 0;
        if (pos + 1 < end) av = Ap[s_nxt * 16 + j];
        s_nxt = s_nn;
        acc += fmaxf(avc + b, 0.f);
    }
    aggp[n * 16 + j] = acc;
}

extern "C" void kernel_launch(void* const* d_in, const int* in_sizes, int n_in,
                              void* d_out, int out_size, void* d_ws, size_t ws_size,
                              hipStream_t stream) {
    (void)in_sizes; (void)n_in; (void)out_size;
    const float* inputs = (const float*)d_in[0];
    const float* e_feats = (const float*)d_in[1];
    const float* rain0 = (const float*)d_in[2];
    const int* src = (const int*)d_in[3];
    const int* dst = (const int*)d_in[4];
    const float* W_emb = (const float*)d_in[5];
    const float* Win_hs = (const float*)d_in[6];
    const float* Win_hd = (const float*)d_in[7];
    const float* Win_e = (const float*)d_in[8];
    const float* Win_r = (const float*)d_in[9];
    const float* Wp_hs = (const float*)d_in[10];
    const float* Wp_hd = (const float*)d_in[11];
    const float* Wp_e = (const float*)d_in[12];
    const float* Wp_r = (const float*)d_in[13];
    const float* Wo_hs = (const float*)d_in[14];
    const float* Wo_hd = (const float*)d_in[15];
    const float* Wo_e = (const float*)d_in[16];
    const float* Wo_r = (const float*)d_in[17];
    const float* W_rain = (const float*)d_in[18];
    float* out = (float*)d_out;

    const size_t NF64 = (size_t)NN * 64;
    const size_t NF16 = (size_t)NN * 16;
    const size_t EF = (size_t)NE * 8;

    const size_t int_bytes = (2 * (size_t)NE + 2 * (size_t)NN + 1 + 128) * 4;
    const size_t need_big = (6 * NF64 + 4 * NF16 + 4 * EF + 128) * 4 + int_bytes;
    const bool big = ws_size >= need_big;

    float* ws = (float*)d_ws;
    float *A, *B, *aggA, *aggB, *aggO, *hemb, *p0, *p1, *Ap, *Bp, *efp, *Wfold;
    if (big) {
        A = ws;    ws += NF64;
        B = ws;    ws += NF64;
        aggA = ws; ws += NF64;
        aggB = ws; ws += NF64;
        aggO = ws; ws += NF64;
        hemb = ws; ws += NF64;
        p0 = ws;   ws += NF16;
        p1 = ws;   ws += NF16;
        Ap = ws;   ws += NF16;
        Bp = ws;   ws += NF16;
        efp = ws;  ws += 4 * EF;
        Wfold = ws; ws += 128;
    } else {
        A = ws;    ws += NF64;
        B = ws;    ws += NF64;
        aggA = ws; ws += NF64;
        aggB = ws; ws += NF64;
        aggO = ws; ws += NF64;
        efp = ws;  ws += EF;
        Wfold = ws; ws += 128;
        hemb = aggO;
        Ap = A;
        Bp = A + NF16;
        p0 = aggA;
        p1 = aggA + NF16;
    }
    int* ip = (int*)ws;
    int* srcp = ip;    ip += NE;
    int* perm = ip;    ip += NE;
    int* rowptr = ip;  ip += NN + 1;
    int* deg = ip;     ip += NN;
    int* bsum = ip;    ip += 64;
    int* boff = ip;    ip += 64;
    int* cursor = deg;

    // ---- CSR build (once) ----
    hipMemsetAsync(deg, 0, NN * sizeof(int), stream);
    hist_kernel<<<(NE + 255) / 256, 256, 0, stream>>>(dst, deg);
    scan1_kernel<<<NBLK_SCAN, 256, 0, stream>>>(deg, bsum);
    scan2_kernel<<<1, 64, 0, stream>>>(bsum, boff, rowptr);
    scan3_kernel<<<NBLK_SCAN, 256, 0, stream>>>(deg, boff, rowptr);
    hipMemcpyAsync(cursor, rowptr, NN * sizeof(int), hipMemcpyDeviceToDevice, stream);
    scatter_kernel<<<(NE + 255) / 256, 256, 0, stream>>>(src, dst, cursor, perm, srcp);
    if (big)
        efperm_all_kernel<<<(NE + 255) / 256, 256, 0, stream>>>(e_feats, perm, efp);

    emb_kernel<<<(NN * 64 + 255) / 256, 256, 0, stream>>>(inputs, W_emb, hemb);
    wfold_kernel<<<1, 128, 0, stream>>>(Wp_e, Wfold);

    for (int t = 0; t < TT; ++t) {
        const float* rain = rain0 + t;
        const float* eft = big ? (efp + (size_t)t * EF) : efp;
        if (!big)
            efperm_one_kernel<<<(NE * 8 + 255) / 256, 256, 0, stream>>>(e_feats, perm, t, efp);

        // ---- IN s=0 ----
        node_ab_kernel<<<1250, 256, 64 * 64 * 2 * sizeof(float), stream>>>(
            (t == 0) ? hemb : aggO, (t > 0) ? 1 : 0, nullptr, 0,
            Win_hs, Win_hd, rain, Win_r, A, B);
        edge64_csr<<<10000, 256, 0, stream>>>(A, B, eft, Win_e, rowptr, srcp, aggA,
                                              nullptr, nullptr, 0);

        // ---- IN s=1 ----
        node_ab_kernel<<<1250, 256, 64 * 64 * 2 * sizeof(float), stream>>>(
            aggA, 1, nullptr, 0, Win_hs + 4096, Win_hd + 4096, rain, Win_r + 64, A, B);
        edge64_csr<<<10000, 256, 0, stream>>>(A, B, eft, Win_e + 512, rowptr, srcp, aggB,
                                              nullptr, nullptr, 0);

        // ---- PROP first call (s=0, edge-level ef with folded weights) ----
        node_p_kernel<<<625, 256, 0, stream>>>(aggB, nullptr, 0, Wp_hs, Wp_hd, nullptr,
                                               rain, Wp_r, Ap, Bp);
        edge16_csr_ef<<<2500, 256, 0, stream>>>(Ap, Bp, eft, Wfold, rowptr, srcp, p0);

        float* pc = p0;
        float* pn = p1;
        for (int s = (t == 0) ? 0 : 1; s < 2; ++s) {
            node_p_kernel<<<625, 256, 0, stream>>>(aggB, pc, 1, Wp_hs + s * 1024,
                                                   Wp_hd + s * 1024, Wp_e + s * 256,
                                                   rain, Wp_r + s * 16, Ap, Bp);
            edge16_csr_pe<<<2500, 256, 0, stream>>>(Ap, Bp, rowptr, srcp, pn);
            float* tmp = pc; pc = pn; pn = tmp;
        }

        // ---- OUT layer (fused rain-output epilogue) ----
        node_ab_kernel<<<1250, 256, 80 * 64 * 2 * sizeof(float), stream>>>(
            aggB, 1, pc, 16, Wo_hs, Wo_hd, rain, Wo_r, A, B);
        edge64_csr<<<10000, 256, 0, stream>>>(A, B, eft, Wo_e, rowptr, srcp, aggO,
                                              W_rain, out, t);
    }
}